// Round 13
// baseline (65.831 us; speedup 1.0000x reference)
//
#include <hip/hip_runtime.h>
#include <stdint.h>

#define NREG   20
#define EDIM   768
#define DVOL   64
#define HVOL   512
#define WVOL   512
#define HW_    (HVOL * WVOL)
#define DHW_   (DVOL * HVOL * WVOL)
#define NPATCH 16384
#define BTOT   2
#define PROTO_N (NREG * EDIM)            // 15360
#define RF_N    (BTOT * PROTO_N)         // 30720 floats (output 0)
#define TOTAL_PATCHES (BTOT * NPATCH)    // 32768
#define NBUCKET 1024                     // 2 b x 32 zbins x 16 ybins

#define SORT_BLOCKS    16                // role 0: counting sort (co-resident)
#define COMPACT_BLOCKS 512               // role 1: int32 -> int8 mask
#define FUSED_BLOCKS   (SORT_BLOCKS + COMPACT_BLOCKS)

// ---- workspace layout ------------------------------------------------------
// [0, 33.5MB): int8 mask; 64B slack; phase word; bcnt[16][1024]; sort arrays.
#define SEG8_BYTES (BTOT * DHW_)                   // 33,554,432
#define W_PHASE    ((SEG8_BYTES / 4) + 16)         // 1 word (memset per launch)
#define W_BCNT     (W_PHASE + 32)                  // 16 x 1024
#define W_PID      (W_BCNT + SORT_BLOCKS * NBUCKET)
#define W_C0       (W_PID  + TOTAL_PATCHES)
#define W_C1       (W_C0   + TOTAL_PATCHES)
#define W_C2       (W_C1   + TOTAL_PATCHES)

__device__ __forceinline__ uint32_t pack4i(int4 v)
{
    return (uint32_t)v.x | ((uint32_t)v.y << 8)
         | ((uint32_t)v.z << 16) | ((uint32_t)v.w << 24);
}

// ---------------------------------------------------------------------------
// Fused kernel, two INDEPENDENT roles (no cross-role sync):
//  blocks [0,16):    global counting sort of patches by (b, z/2, y/32).
//                    16-block barrier via agent-scope phase counter — safe by
//                    capacity (528 blocks x 512 thr all co-resident).
//  blocks [16,528):  streaming int32 -> int8 mask compaction (coalesced).
// ---------------------------------------------------------------------------
__global__ __launch_bounds__(512) void fused_kernel(
    const int*   __restrict__ seg,
    const float* __restrict__ coords,
    unsigned*    __restrict__ ws)
{
    const int bid = (int)blockIdx.x;
    const int t   = (int)threadIdx.x;

    if (bid >= SORT_BLOCKS) {
        // ---------------- role 1: compaction --------------------------------
        uint8_t* seg8 = (uint8_t*)ws;
        const int gid = (bid - SORT_BLOCKS) * 512 + t;
#pragma unroll
        for (int it = 0; it < 8; ++it) {
            const int q = it * (COMPACT_BLOCKS * 512) + gid;  // uint4 index
            const int4* ip = (const int4*)(seg + (size_t)q * 16);
            const int4 v0 = ip[0], v1 = ip[1], v2 = ip[2], v3 = ip[3];
            uint4 w;
            w.x = pack4i(v0); w.y = pack4i(v1);
            w.z = pack4i(v2); w.w = pack4i(v3);
            ((uint4*)seg8)[q] = w;
        }
        return;
    }

    // ---------------- role 0: counting sort ---------------------------------
    __shared__ unsigned hist[NBUCKET];
    __shared__ unsigned sA[NBUCKET], sB[NBUCKET];
    __shared__ unsigned curs[NBUCKET];

    float* wsf = (float*)ws;
    const int blk = bid;                   // 0..15
    const int p0  = blk * 2048 + t * 4;    // 4 consecutive patches per thread
    const int b   = blk >> 3;              // batch (uniform per block)

    hist[t] = 0u; hist[t + 512] = 0u;
    __syncthreads();

    // 4 patches: 12 contiguous floats (48B, 16B-aligned since p0 % 4 == 0)
    float c[12];
    {
        const float4* cp = (const float4*)(coords + (size_t)p0 * 3);
        const float4 a = cp[0], bb = cp[1], d = cp[2];
        c[0]=a.x;  c[1]=a.y;  c[2]=a.z;  c[3]=a.w;  c[4]=bb.x; c[5]=bb.y;
        c[6]=bb.z; c[7]=bb.w; c[8]=d.x;  c[9]=d.y;  c[10]=d.z; c[11]=d.w;
    }
    unsigned key[4];
#pragma unroll
    for (int i = 0; i < 4; ++i) {
        const int zbin = ((int)(c[3*i + 0] * 64.0f))  >> 1;   // 0..31
        const int ybin = ((int)(c[3*i + 1] * 512.0f)) >> 5;   // 0..15
        key[i] = (unsigned)(b * 512 + zbin * 16 + ybin);
        atomicAdd(&hist[key[i]], 1u);
    }
    __syncthreads();

    ws[W_BCNT + blk * NBUCKET + t]       = hist[t];
    ws[W_BCNT + blk * NBUCKET + t + 512] = hist[t + 512];
    __syncthreads();

    if (t == 0) {
        __hip_atomic_fetch_add(&ws[W_PHASE], 1u,
                               __ATOMIC_RELEASE, __HIP_MEMORY_SCOPE_AGENT);
        int guard = 0;
        while (__hip_atomic_load(&ws[W_PHASE],
                 __ATOMIC_ACQUIRE, __HIP_MEMORY_SCOPE_AGENT) < SORT_BLOCKS
               && guard < (1 << 24)) {
            __builtin_amdgcn_s_sleep(1);
            ++guard;
        }
    }
    __syncthreads();

    // totals + this block's "before" share, for buckets t and t+512
    unsigned tot0 = 0u, bef0 = 0u, tot1 = 0u, bef1 = 0u;
#pragma unroll
    for (int k = 0; k < SORT_BLOCKS; ++k) {
        const unsigned v0 = ws[W_BCNT + k * NBUCKET + t];
        const unsigned v1 = ws[W_BCNT + k * NBUCKET + t + 512];
        tot0 += v0; bef0 += (k < blk) ? v0 : 0u;
        tot1 += v1; bef1 += (k < blk) ? v1 : 0u;
    }
    sA[t] = tot0; sA[t + 512] = tot1;
    __syncthreads();

    // inclusive Hillis-Steele scan over 1024 buckets (double-buffered)
    unsigned* src = sA;
    unsigned* dst = sB;
    for (int off = 1; off < NBUCKET; off <<= 1) {
        dst[t]       = src[t]       + ((t       >= off) ? src[t       - off] : 0u);
        dst[t + 512] = src[t + 512] + ((t + 512 >= off) ? src[t + 512 - off] : 0u);
        __syncthreads();
        unsigned* tmp = src; src = dst; dst = tmp;
    }
    curs[t]       = (src[t]       - tot0) + bef0;   // exclusive + block base
    curs[t + 512] = (src[t + 512] - tot1) + bef1;
    __syncthreads();

    // scatter own 4 patches (pid + SoA coords)
#pragma unroll
    for (int i = 0; i < 4; ++i) {
        const unsigned rank = atomicAdd(&curs[key[i]], 1u);
        ws[W_PID + rank] = (unsigned)(p0 + i);
        wsf[W_C0 + rank] = c[3*i + 0];
        wsf[W_C1 + rank] = c[3*i + 1];
        wsf[W_C2 + rank] = c[3*i + 2];
    }
}

// ---------------------------------------------------------------------------
// Assign: one wave per globally-sorted slot; XCD class c sweeps sorted range
// [c*4096,(c+1)*4096) -> its byte-mask slice (~4.2MB) ~ L2-resident.
// Byte-window loads (3 x 8B), funnel shift + masks, packed 8-bit histogram,
// shfl butterfly, in-register finish. Blocks 0..119 also copy prototypes.
// ---------------------------------------------------------------------------
__global__ __launch_bounds__(256) void assign_kernel(
    const unsigned* __restrict__ ws,
    const float*    __restrict__ proto,
    float*          __restrict__ out)
{
    if (blockIdx.x < RF_N / 256) {
        const int i = (int)blockIdx.x * 256 + (int)threadIdx.x;
        out[i] = proto[i >= PROTO_N ? i - PROTO_N : i];
    }

    const uint8_t* seg8 = (const uint8_t*)ws;
    const float*   wsf  = (const float*)ws;

    const int bid  = (int)blockIdx.x;
    const int sbid = (bid & 7) * 1024 + (bid >> 3);

    const int lane = threadIdx.x & 63;
    const int wave = threadIdx.x >> 6;
    const int slot = sbid * 4 + wave;

    const int   patch = (int)ws[W_PID + slot];        // wave-uniform
    const float c0 = wsf[W_C0 + slot] * 64.0f;        // z
    const float c1 = wsf[W_C1 + slot] * 512.0f;       // y
    const float c2 = wsf[W_C2 + slot] * 512.0f;       // x
    const int b = patch >> 14;

    const int sz = (int)fmaxf(0.0f,   floorf(c0 - 2.0f));
    const int ez = (int)fminf(64.0f,  floorf(c0 + 2.0f));
    const int sy = (int)fmaxf(0.0f,   floorf(c1 - 8.0f));
    const int ey = (int)fminf(512.0f, floorf(c1 + 8.0f));
    const int sx = (int)fmaxf(0.0f,   floorf(c2 - 8.0f));
    const int ex = (int)fminf(512.0f, floorf(c2 + 8.0f));

    const int zz = lane >> 4;                 // 0..3
    const int yy = lane & 15;                 // 0..15
    const int zi = sz + zz;
    const int yi = sy + yy;
    const int ziC = min(zi, DVOL - 1);
    const int yiC = min(yi, HVOL - 1);
    const int a0  = sx & ~7;                  // 8B-aligned window base
    const int sh  = (sx & 7) * 8;
    const int rowoff = b * DHW_ + ziC * HW_ + yiC * WVOL;

    const uint8_t* rp = seg8 + (size_t)rowoff + a0;
    const uint64_t u0 = *(const uint64_t*)(rp);
    const uint64_t u1 = *(const uint64_t*)(rp + 8);
    const uint64_t u2 = *(const uint64_t*)(rp + 16);

    uint64_t A  = (u0 >> sh) | (sh ? (u1 << (64 - sh)) : 0ull);
    uint64_t Bv = (u1 >> sh) | (sh ? (u2 << (64 - sh)) : 0ull);

    const int nv  = min(max(ex - sx, 0), 16);
    const int nvB = max(nv - 8, 0);
    uint64_t mA = (nv  >= 8) ? ~0ull : ((1ull << (8 * nv )) - 1ull);
    uint64_t mB = (nvB >= 8) ? ~0ull : ((1ull << (8 * nvB)) - 1ull);
    if (!((yi < ey) & (zi < ez))) { mA = 0ull; mB = 0ull; }
    A &= mA;  Bv &= mB;

    // packed 8-bit histogram: cc[k] holds regions 4k..4k+3 (0-based m)
    unsigned cc[5] = {0u, 0u, 0u, 0u, 0u};
    const uint32_t wd[4] = {(uint32_t)A,  (uint32_t)(A  >> 32),
                            (uint32_t)Bv, (uint32_t)(Bv >> 32)};
#pragma unroll
    for (int d = 0; d < 4; ++d) {
        const uint32_t x = wd[d];
#pragma unroll
        for (int j = 0; j < 4; ++j) {
            const int v = (int)((x >> (8 * j)) & 0xFFu);
            const int tt = v - 1;                      // -1 if not counted
            const unsigned inc = 1u << ((tt & 3) << 3);
            const int qk = tt >> 2;                    // -1 matches no k
#pragma unroll
            for (int k = 0; k < 5; ++k)
                cc[k] += (qk == k) ? inc : 0u;
        }
    }

    // 3-step packed butterfly (8-lane groups; per-lane max 16 -> <=128/field)
#pragma unroll
    for (int off = 1; off < 8; off <<= 1) {
#pragma unroll
        for (int k = 0; k < 5; ++k)
            cc[k] += (unsigned)__shfl_xor((int)cc[k], off);
    }

    // unpack 8-bit -> 2x16-bit, 3 more steps across the 8 groups
    unsigned lo[5], hi[5];
#pragma unroll
    for (int k = 0; k < 5; ++k) {
        lo[k] = cc[k] & 0x00FF00FFu;          // regions 4k (lo16), 4k+2 (hi16)
        hi[k] = (cc[k] >> 8) & 0x00FF00FFu;   // regions 4k+1,      4k+3
    }
#pragma unroll
    for (int off = 8; off < 64; off <<= 1) {
#pragma unroll
        for (int k = 0; k < 5; ++k) {
            lo[k] += (unsigned)__shfl_xor((int)lo[k], off);
            hi[k] += (unsigned)__shfl_xor((int)hi[k], off);
        }
    }

    unsigned S = 0u;
#pragma unroll
    for (int k = 0; k < 5; ++k) S += lo[k] + hi[k];
    const unsigned tot = (S & 0xFFFFu) + (S >> 16);   // <= 1024, no carry

    const int r = lane & 3;
    const unsigned sLo = (lane < 4) ? lo[0] : (lane < 8) ? lo[1]
                       : (lane < 12) ? lo[2] : (lane < 16) ? lo[3] : lo[4];
    const unsigned sHi = (lane < 4) ? hi[0] : (lane < 8) ? hi[1]
                       : (lane < 12) ? hi[2] : (lane < 16) ? hi[3] : hi[4];
    const unsigned fld = (r & 1) ? sHi : sLo;
    const unsigned cnt = (r & 2) ? (fld >> 16) : (fld & 0xFFFFu);

    if (lane < NREG) {
        const float nz = (float)max(ez - sz, 0);
        const float ny = (float)max(ey - sy, 0);
        const float nx = (float)max(ex - sx, 0);
        const float denom = fmaxf(nz * ny * nx, 1.0f);
        const float s = (float)tot / denom + (float)NREG * 1e-6f;
        const float a = (float)cnt / denom + 1e-6f;
        out[RF_N + patch * NREG + lane] = a / s;
    }
}

// ---------------------------------------------------------------------------
extern "C" void kernel_launch(void* const* d_in, const int* in_sizes, int n_in,
                              void* d_out, int out_size, void* d_ws, size_t ws_size,
                              hipStream_t stream)
{
    const int*   seg    = (const int*)d_in[0];
    const float* coords = (const float*)d_in[1];
    const float* proto  = (const float*)d_in[2];
    float*       out    = (float*)d_out;
    unsigned*    ws     = (unsigned*)d_ws;

    hipMemsetAsync(ws + W_PHASE, 0, sizeof(unsigned), stream);  // phase only
    hipLaunchKernelGGL(fused_kernel, dim3(FUSED_BLOCKS), dim3(512),
                       0, stream, seg, coords, ws);
    hipLaunchKernelGGL(assign_kernel, dim3(TOTAL_PATCHES / 4), dim3(256),
                       0, stream, ws, proto, out);
}